// Round 9
// baseline (168.900 us; speedup 1.0000x reference)
//
#include <hip/hip_runtime.h>
#include <math.h>

#define NPTS 100000
#define NVERTS 6890
#define NJ 24

// MFMA tiling: 32 verts per tile, 216 tiles (6912 padded verts), linear layout.
#define NTILE 216
#define TILE_F4 96                    // 1536 B per tile: rec0(512) rec1(512) rec2(512)

typedef short bf16x8 __attribute__((ext_vector_type(8)));
typedef float f32x16 __attribute__((ext_vector_type(16)));

__device__ __forceinline__ unsigned short bf16_rtne(float f) {
    const unsigned int u = __float_as_uint(f);
    return (unsigned short)((u + 0x7FFFu + ((u >> 16) & 1u)) >> 16);
}
__device__ __forceinline__ float bf16_back(unsigned short h) {
    return __uint_as_float(((unsigned int)h) << 16);
}
__device__ __forceinline__ float min3f(float a, float b, float c) {
    float d;
    asm("v_min3_f32 %0, %1, %2, %3" : "=v"(d) : "v"(a), "v"(b), "v"(c));
    return d;
}
__device__ __forceinline__ float min16(const f32x16 a) {
    const float m0 = min3f(a[0], a[1], a[2]);
    const float m1 = min3f(a[3], a[4], a[5]);
    const float m2 = min3f(a[6], a[7], a[8]);
    const float m3 = min3f(a[9], a[10], a[11]);
    const float m4 = min3f(a[12], a[13], a[14]);
    const float n0 = min3f(m0, m1, m2);
    const float n1 = min3f(m3, m4, a[15]);
    return fminf(n0, n1);
}

// ---------------- Kernel 0: prep vert records (A-fragment image, linear t*96) ----------------
// Per vert: rec0 = [vh0,vh1,vh2, vl0,vl1,vl2, vh0,vh1] (A k=0..7, lanes<32)
//           rec1 = [vh2, vsqh, vsql, 1, 1, 0,0,0]      (A k=8..15, lanes>=32)
//           rec2 = (vx,vy,vz,vsq) f32 for the exact-chain slow path.
__global__ void prep_kernel(const float* __restrict__ verts, float4* __restrict__ recG)
{
#pragma clang fp contract(off)
    const int v = blockIdx.x * 256 + threadIdx.x;
    if (v >= NTILE * 32) return;
    const int t_glob = v >> 5, row = v & 31;
    float4* base = recG + t_glob * TILE_F4;

    float cx = 0.f, cy = 0.f, cz = 0.f, vsq;
    unsigned short vh0, vh1, vh2, vl0, vl1, vl2, qh, ql;
    const short one = (short)0x3F80;
    if (v < NVERTS) {
        cx = verts[v * 3 + 0]; cy = verts[v * 3 + 1]; cz = verts[v * 3 + 2];
        vsq = (cx * cx + cy * cy) + cz * cz;
        vh0 = bf16_rtne(cx); vl0 = bf16_rtne(cx - bf16_back(vh0));
        vh1 = bf16_rtne(cy); vl1 = bf16_rtne(cy - bf16_back(vh1));
        vh2 = bf16_rtne(cz); vl2 = bf16_rtne(cz - bf16_back(vh2));
        qh = bf16_rtne(vsq); ql = bf16_rtne(vsq - bf16_back(qh));
    } else {
        vh0 = vh1 = vh2 = vl0 = vl1 = vl2 = 0;
        qh = bf16_rtne(30000.0f); ql = 0; vsq = 1e30f;  // sentinel: never a candidate
    }
    union { bf16x8 s; float4 f; } r0, r1;
    r0.s = (bf16x8){(short)vh0, (short)vh1, (short)vh2,
                    (short)vl0, (short)vl1, (short)vl2, (short)vh0, (short)vh1};
    r1.s = (bf16x8){(short)vh2, (short)qh, (short)ql, one, one, 0, 0, 0};
    base[row]      = r0.f;
    base[32 + row] = r1.f;
    base[64 + row] = make_float4(cx, cy, cz, vsq);
}

// ---------------- Kernel 1: MFMA NN — no LDS, no barriers ----------------
// d~2[i][j] via one mfma_f32_32x32x16_bf16 per 32x32 tile; A-fragment rows loaded
// per-lane straight from recG (L2-resident, coalesced 1KB/wave/tile).
// Phase 1: running min m of d~ over all 216 tiles. Phase 2: candidates
// d~ <= thr = m + tau (tau >= 2E) get the bit-exact reference f32 chain from rec2
// and merge via packed u64 atomicMin -> exactly np.argmin (first-index ties).
__global__ __launch_bounds__(256) void nn_mfma_kernel(
    const float* __restrict__ xyz,
    const float4* __restrict__ recG,
    unsigned long long* __restrict__ best_ws)
{
#pragma clang fp contract(off)
    const int tid = threadIdx.x;
    const int lane = tid & 63;
    const int wid = tid >> 6;
    const int half = lane >> 5;
    const int col = lane & 31;

    const int p = blockIdx.x * 128 + wid * 32 + col;
    const int pe = (p < NPTS) ? p : (NPTS - 1);
    const float x = xyz[pe * 3 + 0], y = xyz[pe * 3 + 1], z = xyz[pe * 3 + 2];
    const float xsq = (x * x + y * y) + z * z;   // exact ref sequence

    // B fragment (point side): lanes<32 hold K 0..7, lanes>=32 K 8..15
    const float ux = -2.0f * x, uy = -2.0f * y, uz = -2.0f * z;
    const unsigned short uh0 = bf16_rtne(ux), uh1 = bf16_rtne(uy), uh2 = bf16_rtne(uz);
    const unsigned short ul0 = bf16_rtne(ux - bf16_back(uh0));
    const unsigned short ul1 = bf16_rtne(uy - bf16_back(uh1));
    const unsigned short ul2 = bf16_rtne(uz - bf16_back(uh2));
    const unsigned short qh = bf16_rtne(xsq);
    const unsigned short ql = bf16_rtne(xsq - bf16_back(qh));
    const short one = (short)0x3F80;
    bf16x8 bfrag;
    if (half == 0)
        bfrag = (bf16x8){(short)uh0, (short)uh1, (short)uh2,
                         (short)uh0, (short)uh1, (short)uh2, (short)ul0, (short)ul1};
    else
        bfrag = (bf16x8){(short)ul2, one, one, (short)qh, (short)ql, 0, 0, 0};

    const f32x16 zacc = {0.f};
    const int aoff = half * 32 + col;   // rec0/rec1 row within tile

    // ---- phase 1: min of d~ over all verts (no barriers, loads pipelined) ----
    float run = 1e30f;
    #pragma unroll 2
    for (int t = 0; t < NTILE; ++t) {
        union { float4 f; bf16x8 s; } a;
        a.f = recG[t * TILE_F4 + aoff];
        const f32x16 acc = __builtin_amdgcn_mfma_f32_32x32x16_bf16(a.s, bfrag, zacc, 0, 0, 0);
        run = fminf(run, min16(acc));
    }
    const float m = fminf(run, __shfl_xor(run, 32));
    const float thr = m + (1.5e-4f + 1.5e-4f * xsq + 1.0e-4f * m);  // >= m + 2E

    // ---- phase 2: exact-chain resolve of all candidates ----
    #pragma unroll 2
    for (int t = 0; t < NTILE; ++t) {
        union { float4 f; bf16x8 s; } a;
        a.f = recG[t * TILE_F4 + aoff];
        const f32x16 acc = __builtin_amdgcn_mfma_f32_32x32x16_bf16(a.s, bfrag, zacc, 0, 0, 0);
        if (min16(acc) <= thr) {
            #pragma unroll
            for (int e = 0; e < 16; ++e) {
                if (acc[e] <= thr) {
                    const int row = (e & 3) + 8 * (e >> 2) + 4 * half;
                    const float4 vr = recG[t * TILE_F4 + 64 + row];
                    // bit-exact reference chain
                    float g = x * vr.x;
                    g = fmaf(y, vr.y, g);
                    g = fmaf(z, vr.z, g);
                    const float tt = fmaf(-2.0f, g, xsq);
                    const float d2 = tt + vr.w;
                    const int vg = t * 32 + row;
                    const unsigned long long pk =
                        ((unsigned long long)__float_as_uint(d2) << 32) | (unsigned)vg;
                    atomicMin(&best_ws[pe], pk);
                }
            }
        }
    }
}

// ---------------- Kernel 2: per-point skinning + quaternion + outputs ----------------
__global__ __launch_bounds__(256) void apply_kernel(
    const float* __restrict__ xyz,
    const float* __restrict__ rot,
    const float* __restrict__ sw,
    const float* __restrict__ tm,
    const unsigned long long* __restrict__ best_ws,
    float* __restrict__ out)
{
    __shared__ float tl[NJ * 16];
    const int tid = threadIdx.x;
    for (int i = tid; i < NJ * 16; i += 256) tl[i] = tm[i];
    __syncthreads();

    const int p = blockIdx.x * 256 + tid;
    if (p >= NPTS) return;

    const int vi = (int)(best_ws[p] & 0xFFFFFFFFull);
    const float4* w4 = reinterpret_cast<const float4*>(sw + (size_t)vi * NJ);

    float T[16];
    #pragma unroll
    for (int i = 0; i < 16; ++i) T[i] = 0.0f;

    #pragma unroll
    for (int jq = 0; jq < NJ / 4; ++jq) {
        const float4 wv = w4[jq];
        const float wj[4] = { wv.x, wv.y, wv.z, wv.w };
        #pragma unroll
        for (int k = 0; k < 4; ++k) {
            const int j = jq * 4 + k;
            #pragma unroll
            for (int i = 0; i < 16; ++i)
                T[i] = fmaf(wj[k], tl[j * 16 + i], T[i]);
        }
    }

    const float4 q = reinterpret_cast<const float4*>(rot)[p];
    float qr = q.x, qx = q.y, qy = q.z, qz = q.w;
    const float inv = 1.0f / sqrtf(qr * qr + qx * qx + qy * qy + qz * qz);
    qr *= inv; qx *= inv; qy *= inv; qz *= inv;
    float R[9];
    R[0] = 1.0f - 2.0f * (qy * qy + qz * qz);
    R[1] = 2.0f * (qx * qy - qr * qz);
    R[2] = 2.0f * (qx * qz + qr * qy);
    R[3] = 2.0f * (qx * qy + qr * qz);
    R[4] = 1.0f - 2.0f * (qx * qx + qz * qz);
    R[5] = 2.0f * (qy * qz - qr * qx);
    R[6] = 2.0f * (qx * qz - qr * qy);
    R[7] = 2.0f * (qy * qz + qr * qx);
    R[8] = 1.0f - 2.0f * (qx * qx + qy * qy);

    const float x0 = xyz[p * 3 + 0];
    const float x1 = xyz[p * 3 + 1];
    const float x2 = xyz[p * 3 + 2];

    #pragma unroll
    for (int i = 0; i < 3; ++i) {
        out[p * 3 + i] = fmaf(T[i * 4 + 0], x0,
                          fmaf(T[i * 4 + 1], x1,
                           fmaf(T[i * 4 + 2], x2, T[i * 4 + 3])));
    }

    float* rb = out + 300000 + (size_t)p * 9;
    #pragma unroll
    for (int i = 0; i < 3; ++i) {
        #pragma unroll
        for (int k = 0; k < 3; ++k) {
            rb[i * 3 + k] = fmaf(T[i * 4 + 0], R[0 * 3 + k],
                             fmaf(T[i * 4 + 1], R[1 * 3 + k],
                                  T[i * 4 + 2] * R[2 * 3 + k]));
        }
    }

    float* tb = out + 1200000 + (size_t)p * 16;
    #pragma unroll
    for (int i = 0; i < 16; ++i) tb[i] = T[i];
}

extern "C" void kernel_launch(void* const* d_in, const int* in_sizes, int n_in,
                              void* d_out, int out_size, void* d_ws, size_t ws_size,
                              hipStream_t stream) {
    const float* xyz   = (const float*)d_in[0];
    const float* rot   = (const float*)d_in[1];
    const float* verts = (const float*)d_in[2];
    const float* sw    = (const float*)d_in[3];
    const float* tm    = (const float*)d_in[4];
    float* out = (float*)d_out;

    unsigned long long* best_ws = (unsigned long long*)d_ws;            // 800 KB
    float4* recG = (float4*)((char*)d_ws + (1 << 20));                  // 332 KB

    hipMemsetAsync(d_ws, 0xFF, NPTS * sizeof(unsigned long long), stream);

    prep_kernel<<<(NTILE * 32 + 255) / 256, 256, 0, stream>>>(verts, recG);
    nn_mfma_kernel<<<(NPTS + 127) / 128, 256, 0, stream>>>(xyz, recG, best_ws);
    apply_kernel<<<(NPTS + 255) / 256, 256, 0, stream>>>(xyz, rot, sw, tm, best_ws, out);
}

// Round 10
// 145.727 us; speedup vs baseline: 1.1590x; 1.1590x over previous
//
#include <hip/hip_runtime.h>
#include <math.h>

#define NPTS 100000
#define NVERTS 6890
#define NJ 24

// MFMA tiling: 32 verts per tile, 216 tiles (6912 padded verts), linear layout.
#define NTILE 216
#define TILE_F4 96                    // 1536 B per tile: rec0(512) rec1(512) rec2(512)
#define TSPLIT 4                      // tile-dim split across blockIdx.y
#define TPS (NTILE / TSPLIT)          // 54 tiles per split

typedef short bf16x8 __attribute__((ext_vector_type(8)));
typedef float f32x16 __attribute__((ext_vector_type(16)));

__device__ __forceinline__ unsigned short bf16_rtne(float f) {
    const unsigned int u = __float_as_uint(f);
    return (unsigned short)((u + 0x7FFFu + ((u >> 16) & 1u)) >> 16);
}
__device__ __forceinline__ float bf16_back(unsigned short h) {
    return __uint_as_float(((unsigned int)h) << 16);
}
__device__ __forceinline__ float min3f(float a, float b, float c) {
    float d;
    asm("v_min3_f32 %0, %1, %2, %3" : "=v"(d) : "v"(a), "v"(b), "v"(c));
    return d;
}
__device__ __forceinline__ float min16(const f32x16 a) {
    const float m0 = min3f(a[0], a[1], a[2]);
    const float m1 = min3f(a[3], a[4], a[5]);
    const float m2 = min3f(a[6], a[7], a[8]);
    const float m3 = min3f(a[9], a[10], a[11]);
    const float m4 = min3f(a[12], a[13], a[14]);
    const float n0 = min3f(m0, m1, m2);
    const float n1 = min3f(m3, m4, a[15]);
    return fminf(n0, n1);
}

// ---------------- Kernel 0: prep vert records (A-fragment image, linear t*96) ----------------
// Per vert: rec0 = [vh0,vh1,vh2, vl0,vl1,vl2, vh0,vh1] (A k=0..7, lanes<32)
//           rec1 = [vh2, vsqh, vsql, 1, 1, 0,0,0]      (A k=8..15, lanes>=32)
//           rec2 = (vx,vy,vz,vsq) f32 for the exact-chain slow path.
__global__ void prep_kernel(const float* __restrict__ verts, float4* __restrict__ recG)
{
#pragma clang fp contract(off)
    const int v = blockIdx.x * 256 + threadIdx.x;
    if (v >= NTILE * 32) return;
    const int t_glob = v >> 5, row = v & 31;
    float4* base = recG + t_glob * TILE_F4;

    float cx = 0.f, cy = 0.f, cz = 0.f, vsq;
    unsigned short vh0, vh1, vh2, vl0, vl1, vl2, qh, ql;
    const short one = (short)0x3F80;
    if (v < NVERTS) {
        cx = verts[v * 3 + 0]; cy = verts[v * 3 + 1]; cz = verts[v * 3 + 2];
        vsq = (cx * cx + cy * cy) + cz * cz;
        vh0 = bf16_rtne(cx); vl0 = bf16_rtne(cx - bf16_back(vh0));
        vh1 = bf16_rtne(cy); vl1 = bf16_rtne(cy - bf16_back(vh1));
        vh2 = bf16_rtne(cz); vl2 = bf16_rtne(cz - bf16_back(vh2));
        qh = bf16_rtne(vsq); ql = bf16_rtne(vsq - bf16_back(qh));
    } else {
        vh0 = vh1 = vh2 = vl0 = vl1 = vl2 = 0;
        qh = bf16_rtne(30000.0f); ql = 0; vsq = 1e30f;  // sentinel: never a candidate
    }
    union { bf16x8 s; float4 f; } r0, r1;
    r0.s = (bf16x8){(short)vh0, (short)vh1, (short)vh2,
                    (short)vl0, (short)vl1, (short)vl2, (short)vh0, (short)vh1};
    r1.s = (bf16x8){(short)vh2, (short)qh, (short)ql, one, one, 0, 0, 0};
    base[row]      = r0.f;
    base[32 + row] = r1.f;
    base[64 + row] = make_float4(cx, cy, cz, vsq);
}

// ---------------- Kernel 1: MFMA NN — tile-split for TLP, no LDS, no barriers ----------------
// blockIdx.y selects a 54-tile quarter. Per-subset proof: for the true argmin w* in this
// subset, d~_{w*} <= m_H + 2E (m_H = d~ of some u with d_u >= d_{w*}-E... ), so phase 2
// with thr = m_H + tau (tau >= 2E) always exact-evaluates w*; packed u64 atomicMin over
// all subsets -> exactly np.argmin (first-index ties). 12.2 waves/SIMD for latency hiding.
__global__ __launch_bounds__(256) void nn_mfma_kernel(
    const float* __restrict__ xyz,
    const float4* __restrict__ recG,
    unsigned long long* __restrict__ best_ws)
{
#pragma clang fp contract(off)
    const int tid = threadIdx.x;
    const int lane = tid & 63;
    const int wid = tid >> 6;
    const int half = lane >> 5;
    const int col = lane & 31;
    const int tbase = blockIdx.y * TPS;

    const int p = blockIdx.x * 128 + wid * 32 + col;
    const int pe = (p < NPTS) ? p : (NPTS - 1);
    const float x = xyz[pe * 3 + 0], y = xyz[pe * 3 + 1], z = xyz[pe * 3 + 2];
    const float xsq = (x * x + y * y) + z * z;   // exact ref sequence

    // B fragment (point side): lanes<32 hold K 0..7, lanes>=32 K 8..15
    const float ux = -2.0f * x, uy = -2.0f * y, uz = -2.0f * z;
    const unsigned short uh0 = bf16_rtne(ux), uh1 = bf16_rtne(uy), uh2 = bf16_rtne(uz);
    const unsigned short ul0 = bf16_rtne(ux - bf16_back(uh0));
    const unsigned short ul1 = bf16_rtne(uy - bf16_back(uh1));
    const unsigned short ul2 = bf16_rtne(uz - bf16_back(uh2));
    const unsigned short qh = bf16_rtne(xsq);
    const unsigned short ql = bf16_rtne(xsq - bf16_back(qh));
    const short one = (short)0x3F80;
    bf16x8 bfrag;
    if (half == 0)
        bfrag = (bf16x8){(short)uh0, (short)uh1, (short)uh2,
                         (short)uh0, (short)uh1, (short)uh2, (short)ul0, (short)ul1};
    else
        bfrag = (bf16x8){(short)ul2, one, one, (short)qh, (short)ql, 0, 0, 0};

    const f32x16 zacc = {0.f};
    const int aoff = half * 32 + col;   // rec0/rec1 row within tile

    // ---- phase 1: min of d~ over this quarter's verts ----
    float run = 1e30f;
    #pragma unroll 2
    for (int tt = 0; tt < TPS; ++tt) {
        const int t = tbase + tt;
        union { float4 f; bf16x8 s; } a;
        a.f = recG[t * TILE_F4 + aoff];
        const f32x16 acc = __builtin_amdgcn_mfma_f32_32x32x16_bf16(a.s, bfrag, zacc, 0, 0, 0);
        run = fminf(run, min16(acc));
    }
    const float m = fminf(run, __shfl_xor(run, 32));
    const float thr = m + (1.5e-4f + 1.5e-4f * xsq + 1.0e-4f * m);  // >= m + 2E

    // ---- phase 2: exact-chain resolve of this quarter's candidates ----
    #pragma unroll 2
    for (int tt = 0; tt < TPS; ++tt) {
        const int t = tbase + tt;
        union { float4 f; bf16x8 s; } a;
        a.f = recG[t * TILE_F4 + aoff];
        const f32x16 acc = __builtin_amdgcn_mfma_f32_32x32x16_bf16(a.s, bfrag, zacc, 0, 0, 0);
        if (min16(acc) <= thr) {
            #pragma unroll
            for (int e = 0; e < 16; ++e) {
                if (acc[e] <= thr) {
                    const int row = (e & 3) + 8 * (e >> 2) + 4 * half;
                    const float4 vr = recG[t * TILE_F4 + 64 + row];
                    // bit-exact reference chain
                    float g = x * vr.x;
                    g = fmaf(y, vr.y, g);
                    g = fmaf(z, vr.z, g);
                    const float tt2 = fmaf(-2.0f, g, xsq);
                    const float d2 = tt2 + vr.w;
                    const int vg = t * 32 + row;
                    const unsigned long long pk =
                        ((unsigned long long)__float_as_uint(d2) << 32) | (unsigned)vg;
                    atomicMin(&best_ws[pe], pk);
                }
            }
        }
    }
}

// ---------------- Kernel 2: per-point skinning + quaternion + outputs ----------------
__global__ __launch_bounds__(256) void apply_kernel(
    const float* __restrict__ xyz,
    const float* __restrict__ rot,
    const float* __restrict__ sw,
    const float* __restrict__ tm,
    const unsigned long long* __restrict__ best_ws,
    float* __restrict__ out)
{
    __shared__ float tl[NJ * 16];
    const int tid = threadIdx.x;
    for (int i = tid; i < NJ * 16; i += 256) tl[i] = tm[i];
    __syncthreads();

    const int p = blockIdx.x * 256 + tid;
    if (p >= NPTS) return;

    const int vi = (int)(best_ws[p] & 0xFFFFFFFFull);
    const float4* w4 = reinterpret_cast<const float4*>(sw + (size_t)vi * NJ);

    float T[16];
    #pragma unroll
    for (int i = 0; i < 16; ++i) T[i] = 0.0f;

    #pragma unroll
    for (int jq = 0; jq < NJ / 4; ++jq) {
        const float4 wv = w4[jq];
        const float wj[4] = { wv.x, wv.y, wv.z, wv.w };
        #pragma unroll
        for (int k = 0; k < 4; ++k) {
            const int j = jq * 4 + k;
            #pragma unroll
            for (int i = 0; i < 16; ++i)
                T[i] = fmaf(wj[k], tl[j * 16 + i], T[i]);
        }
    }

    const float4 q = reinterpret_cast<const float4*>(rot)[p];
    float qr = q.x, qx = q.y, qy = q.z, qz = q.w;
    const float inv = 1.0f / sqrtf(qr * qr + qx * qx + qy * qy + qz * qz);
    qr *= inv; qx *= inv; qy *= inv; qz *= inv;
    float R[9];
    R[0] = 1.0f - 2.0f * (qy * qy + qz * qz);
    R[1] = 2.0f * (qx * qy - qr * qz);
    R[2] = 2.0f * (qx * qz + qr * qy);
    R[3] = 2.0f * (qx * qy + qr * qz);
    R[4] = 1.0f - 2.0f * (qx * qx + qz * qz);
    R[5] = 2.0f * (qy * qz - qr * qx);
    R[6] = 2.0f * (qx * qz - qr * qy);
    R[7] = 2.0f * (qy * qz + qr * qx);
    R[8] = 1.0f - 2.0f * (qx * qx + qy * qy);

    const float x0 = xyz[p * 3 + 0];
    const float x1 = xyz[p * 3 + 1];
    const float x2 = xyz[p * 3 + 2];

    #pragma unroll
    for (int i = 0; i < 3; ++i) {
        out[p * 3 + i] = fmaf(T[i * 4 + 0], x0,
                          fmaf(T[i * 4 + 1], x1,
                           fmaf(T[i * 4 + 2], x2, T[i * 4 + 3])));
    }

    float* rb = out + 300000 + (size_t)p * 9;
    #pragma unroll
    for (int i = 0; i < 3; ++i) {
        #pragma unroll
        for (int k = 0; k < 3; ++k) {
            rb[i * 3 + k] = fmaf(T[i * 4 + 0], R[0 * 3 + k],
                             fmaf(T[i * 4 + 1], R[1 * 3 + k],
                                  T[i * 4 + 2] * R[2 * 3 + k]));
        }
    }

    float* tb = out + 1200000 + (size_t)p * 16;
    #pragma unroll
    for (int i = 0; i < 16; ++i) tb[i] = T[i];
}

extern "C" void kernel_launch(void* const* d_in, const int* in_sizes, int n_in,
                              void* d_out, int out_size, void* d_ws, size_t ws_size,
                              hipStream_t stream) {
    const float* xyz   = (const float*)d_in[0];
    const float* rot   = (const float*)d_in[1];
    const float* verts = (const float*)d_in[2];
    const float* sw    = (const float*)d_in[3];
    const float* tm    = (const float*)d_in[4];
    float* out = (float*)d_out;

    unsigned long long* best_ws = (unsigned long long*)d_ws;            // 800 KB
    float4* recG = (float4*)((char*)d_ws + (1 << 20));                  // 332 KB

    hipMemsetAsync(d_ws, 0xFF, NPTS * sizeof(unsigned long long), stream);

    prep_kernel<<<(NTILE * 32 + 255) / 256, 256, 0, stream>>>(verts, recG);
    dim3 grid((NPTS + 127) / 128, TSPLIT);  // 782 x 4 = 3128 blocks, ~12 waves/SIMD
    nn_mfma_kernel<<<grid, 256, 0, stream>>>(xyz, recG, best_ws);
    apply_kernel<<<(NPTS + 255) / 256, 256, 0, stream>>>(xyz, rot, sw, tm, best_ws, out);
}